// Round 7
// baseline (455.419 us; speedup 1.0000x reference)
//
#include <hip/hip_runtime.h>

#define NH 12
#define HD 32
#define DIMC 384
#define BATCH 32
#define HWIMG 56
#define NWIN 2048          // 32 batches * 64 windows
#define NROWS 100352       // NWIN * 49, dense window-gathered rows
#define QKV_M 1152
#define KDIM 384
#define QSCALE 0.17677669529663687f

typedef __attribute__((ext_vector_type(8))) short short8;
typedef __attribute__((ext_vector_type(4))) short short4v;
typedef __attribute__((ext_vector_type(4))) float f32x4;

typedef const __attribute__((address_space(1))) unsigned int* gas_ptr;
typedef __attribute__((address_space(3))) unsigned int* las_ptr;

__device__ __forceinline__ unsigned short f2bf(float f) {
    union { float f; unsigned u; } v; v.f = f;
    unsigned r = v.u + 0x7FFF + ((v.u >> 16) & 1);
    return (unsigned short)(r >> 16);
}

// ---------------- fp32 -> bf16 weight convert ----------------
__global__ __launch_bounds__(256) void cvt_w(const float* __restrict__ in,
                                             unsigned short* __restrict__ out, int n) {
    int i = blockIdx.x * 256 + threadIdx.x;
    if (i < n) out[i] = f2bf(in[i]);
}

// ---------------- x [B,384,56,56] fp32 -> xt [NROWS,384] bf16 (window-gathered) -------
__global__ __launch_bounds__(256) void cvt_x(const float* __restrict__ x,
                                             unsigned short* __restrict__ xt) {
    __shared__ float tile[32][33];
    const int b = blockIdx.z, c0 = blockIdx.y * 32, n0 = blockIdx.x * 32;
    const int tid = threadIdx.x;
    const int cl = tid >> 5, nl = tid & 31;
    #pragma unroll
    for (int p = 0; p < 4; ++p)
        tile[cl + p * 8][nl] = x[((size_t)b * DIMC + c0 + cl + p * 8) * 3136 + n0 + nl];
    __syncthreads();
    const int nl2 = tid >> 3, cq = (tid & 7) * 4;
    const int n = n0 + nl2;
    const int nh = n / HWIMG, nw = n % HWIMG;
    const int row = ((b * 64 + (nh / 7) * 8 + nw / 7) * 49 + (nh % 7) * 7 + nw % 7);
    short4v pk;
    #pragma unroll
    for (int u = 0; u < 4; ++u) pk[u] = (short)f2bf(tile[cq + u][nl2]);
    *(short4v*)(xt + (size_t)row * KDIM + c0 + cq) = pk;
}

// ---------------- bias expand: biasp[h][j:64][i:64] fp32, transposed & padded ----------
__global__ __launch_bounds__(256) void fill_bias(const float* __restrict__ bias_table,
                                                 const int* __restrict__ rel_index,
                                                 float* __restrict__ biasp) {
    int id = blockIdx.x * 256 + threadIdx.x;   // 12*4096
    int h = id >> 12, r = id & 4095;
    int j = r >> 6, i = r & 63;
    float v = 0.f;
    if (i < 49 && j < 49) v = bias_table[rel_index[i * 49 + j] * NH + h];
    biasp[id] = v;
}

// ---------------- zero the j-pad of vw ----------------
__global__ __launch_bounds__(256) void zero_vpad(unsigned short* __restrict__ vw) {
    int r = blockIdx.x * 256 + threadIdx.x;    // 2048*384 rows
    unsigned short* p = vw + (size_t)r * 64;
    p[49] = 0;
    unsigned* p4 = (unsigned*)(p + 50);
    #pragma unroll
    for (int u = 0; u < 7; ++u) p4[u] = 0;
}

// ---------------- persistent-A n-streaming bf16 MFMA GEMM ----------------
// Block owns 64 m-rows; A[64][384] persists in LDS (48KB).  Streams NTB n-tiles
// of 128 through a 2x16KB B double-buffer with counted vmcnt(4) -> continuous
// NTB*6-step K-pipeline (no per-tile prologue).  2 blocks/CU (80KB LDS).
// MODE 0 (QKV): m<768 -> qkw[ng*768+m] bf16 (m<384 scaled by QSCALE);
//               m>=768 -> vw[(ng/49)*24576 + (m-768)*64 + ng%49] bf16
// MODE 1 (proj): fp32 NCHW + bias; B rows are spatial-major (ng = b*3136+nsp)
template<int MODE>
__global__ __launch_bounds__(256, 2) void gemm_pa(
    const unsigned short* __restrict__ A,
    const unsigned short* __restrict__ Bm,
    const float* __restrict__ bias,
    void* __restrict__ Cout,
    unsigned short* __restrict__ Cv)
{
    __shared__ char Ap[49152];      // 64 rows x 768B (K=384), XOR-swizzled 16B slots
    __shared__ char Bb[2][16384];   // dbuf: 128 n-rows x 128B (K-step 64)
    const int tid = threadIdx.x;

    constexpr int MT  = (MODE == 0) ? 18 : 6;    // 64-row m-chunks
    constexpr int NTB = (MODE == 0) ? 8 : 4;     // n-tiles per block
    constexpr int NS  = NTB * 6;

    // bijective XCD swizzle (works for any nwg), m-fastest within XCD chunk
    const unsigned nwg = gridDim.x, lin = blockIdx.x;
    const unsigned q = nwg >> 3, r = nwg & 7, xcd = lin & 7;
    const unsigned base = (xcd < r) ? xcd * (q + 1) : r * (q + 1) + (xcd - r) * q;
    const unsigned swz = base + (lin >> 3);
    const int m0 = (int)(swz % MT) * 64;
    const int nc = (int)(swz / MT);

    const int lane = tid & 63;
    const int wv = tid >> 6;
    const int wr = wv >> 1, wc = wv & 1;         // wave tile: 32m x 64n
    const int lrow = lane & 15, kgrp = lane >> 4;

    const char* Abase  = (const char*)A + (size_t)m0 * 768;
    const char* Bbase0 = (const char*)Bm + (size_t)nc * NTB * 128 * 768;

    // stage persistent A: 64 rows x 48 slots = 3072 chunks, 12 per thread
    #pragma unroll
    for (int it = 0; it < 12; ++it) {
        int chunk = it * 256 + tid;
        int row = chunk / 48, cs = chunk % 48;
        int scol = (cs >> 3) * 128 + (((cs & 7) ^ (row & 7)) * 16);
        __builtin_amdgcn_global_load_lds(
            (gas_ptr)(Abase + (size_t)row * 768 + scol),
            (las_ptr)(Ap + chunk * 16), 16, 0, 0);
    }

    // stage one B K-chunk: 128 rows x 8 slots = 1024 chunks, 4 per thread
    auto stageB = [&](int nt, int kt, int bufi) {
        const char* Bc = Bbase0 + (size_t)nt * (128 * 768);
        #pragma unroll
        for (int it = 0; it < 4; ++it) {
            int chunk = it * 256 + tid;
            int row = chunk >> 3, sl = chunk & 7;
            int scol = kt * 128 + ((sl ^ (row & 7)) * 16);
            __builtin_amdgcn_global_load_lds(
                (gas_ptr)(Bc + (size_t)row * 768 + scol),
                (las_ptr)(Bb[bufi] + chunk * 16), 16, 0, 0);
        }
    };

    stageB(0, 0, 0);

    f32x4 acc[2][4] = {};
    unsigned short* qk = (unsigned short*)Cout;

    for (int nt = 0; nt < NTB; ++nt) {
        #pragma unroll
        for (int kt = 0; kt < 6; ++kt) {
            const int s = nt * 6 + kt;
            __builtin_amdgcn_s_barrier();        // all waves done reading buf[(kt+1)&1]
            if (s + 1 < NS) {
                stageB(kt == 5 ? nt + 1 : nt, kt == 5 ? 0 : kt + 1, (kt + 1) & 1);
                asm volatile("s_waitcnt vmcnt(4)" ::: "memory");   // older stage landed
            } else {
                asm volatile("s_waitcnt vmcnt(0)" ::: "memory");
            }
            __builtin_amdgcn_s_barrier();        // buf[kt&1] ready for every wave
            const char* Bl = Bb[kt & 1];
            #pragma unroll
            for (int kk = 0; kk < 2; ++kk) {
                short8 af[2], bfr[4];
                #pragma unroll
                for (int i = 0; i < 2; ++i) {
                    int row = wr * 32 + i * 16 + lrow;
                    int slot = (kk * 4 + kgrp) ^ (row & 7);
                    af[i] = *(const short8*)(Ap + row * 768 + kt * 128 + slot * 16);
                }
                #pragma unroll
                for (int j = 0; j < 4; ++j) {
                    int row = wc * 64 + j * 16 + lrow;
                    int slot = (kk * 4 + kgrp) ^ (row & 7);
                    bfr[j] = *(const short8*)(Bl + row * 128 + slot * 16);
                }
                __builtin_amdgcn_s_setprio(1);
                #pragma unroll
                for (int i = 0; i < 2; ++i)
                    #pragma unroll
                    for (int j = 0; j < 4; ++j)
                        acc[i][j] = __builtin_amdgcn_mfma_f32_16x16x32_bf16(af[i], bfr[j], acc[i][j], 0, 0, 0);
                __builtin_amdgcn_s_setprio(0);
            }
        }

        // ---- epilogue for n-tile nt (stores overlap next tile's B prefetch) ----
        const int ng0 = nc * NTB * 128 + nt * 128;
        if (MODE == 0) {
            const float sc = (m0 < 384) ? QSCALE : 1.0f;
            #pragma unroll
            for (int i = 0; i < 2; ++i) {
                int m = m0 + wr * 32 + i * 16 + kgrp * 4;
                #pragma unroll
                for (int j = 0; j < 4; ++j) {
                    int ng = ng0 + wc * 64 + j * 16 + lrow;
                    if (m < 768) {
                        short4v pk;
                        pk.x = (short)f2bf(acc[i][j].x * sc);
                        pk.y = (short)f2bf(acc[i][j].y * sc);
                        pk.z = (short)f2bf(acc[i][j].z * sc);
                        pk.w = (short)f2bf(acc[i][j].w * sc);
                        *(short4v*)(qk + (size_t)ng * 768 + m) = pk;
                    } else {
                        unsigned win = (unsigned)ng / 49u;
                        unsigned ii = (unsigned)ng - win * 49u;
                        unsigned short* vb = Cv + (size_t)win * 24576 + (size_t)(m - 768) * 64 + ii;
                        vb[0]   = f2bf(acc[i][j].x);
                        vb[64]  = f2bf(acc[i][j].y);
                        vb[128] = f2bf(acc[i][j].z);
                        vb[192] = f2bf(acc[i][j].w);
                    }
                    acc[i][j] = f32x4{0.f, 0.f, 0.f, 0.f};
                }
            }
        } else {
            float* C = (float*)Cout;
            #pragma unroll
            for (int i = 0; i < 2; ++i) {
                int m = m0 + wr * 32 + i * 16 + kgrp * 4;
                float b0 = bias[m + 0], b1 = bias[m + 1], b2 = bias[m + 2], b3 = bias[m + 3];
                #pragma unroll
                for (int j = 0; j < 4; ++j) {
                    int ng = ng0 + wc * 64 + j * 16 + lrow;
                    unsigned bb = (unsigned)ng / 3136u;
                    unsigned nsp = (unsigned)ng - bb * 3136u;
                    C[((size_t)bb * DIMC + m + 0) * 3136 + nsp] = acc[i][j].x + b0;
                    C[((size_t)bb * DIMC + m + 1) * 3136 + nsp] = acc[i][j].y + b1;
                    C[((size_t)bb * DIMC + m + 2) * 3136 + nsp] = acc[i][j].z + b2;
                    C[((size_t)bb * DIMC + m + 3) * 3136 + nsp] = acc[i][j].w + b3;
                    acc[i][j] = f32x4{0.f, 0.f, 0.f, 0.f};
                }
            }
        }
    }
}

// ---------------- MFMA windowed attention: one wave per (window, head), no LDS -------
// Output att is SPATIAL-major: row = b*3136 + nsp  (so GEMM2 stores coalesce)
__global__ __launch_bounds__(256) void win_attn(
    const unsigned short* __restrict__ qkw,   // [NROWS][768], q pre-scaled, win-major
    const unsigned short* __restrict__ vw,    // [NWIN][384][64]
    const float* __restrict__ biasp,          // [12][64][64]  (j-major, transposed)
    unsigned short* __restrict__ att)         // [B*3136][384] spatial-major
{
    const int tid = threadIdx.x;
    const int lane = tid & 63;
    const int g = lane >> 4, c = lane & 15;
    const int bid = blockIdx.x;
    const int swz = (bid & 7) * 768 + (bid >> 3);       // 6144 blocks
    const int W = swz * 4 + (tid >> 6);
    const int win = W / 12;
    const int head = W - win * 12;

    const unsigned short* qbase = qkw + (size_t)win * 49 * 768 + head * HD;

    short8 kf[4], qf[4];
    #pragma unroll
    for (int a = 0; a < 4; ++a) {
        int r = a * 16 + c; if (r > 48) r = 48;
        kf[a] = *(const short8*)(qbase + (size_t)r * 768 + DIMC + g * 8);
        qf[a] = *(const short8*)(qbase + (size_t)r * 768 + g * 8);
    }

    // S^T fragments: rows j = a*16+g*4+e, cols i = bi*16+c
    f32x4 s[4][4] = {};
    #pragma unroll
    for (int a = 0; a < 4; ++a)
        #pragma unroll
        for (int bi = 0; bi < 4; ++bi)
            s[a][bi] = __builtin_amdgcn_mfma_f32_16x16x32_bf16(kf[a], qf[bi], s[a][bi], 0, 0, 0);

    const float* bp = biasp + head * 4096;
    #pragma unroll
    for (int bi = 0; bi < 4; ++bi) {
        float mx = -1e30f;
        #pragma unroll
        for (int a = 0; a < 4; ++a) {
            #pragma unroll
            for (int e = 0; e < 4; ++e) {
                int j = a * 16 + g * 4 + e;
                float sv = s[a][bi][e] + bp[j * 64 + bi * 16 + c];
                sv = (j < 49) ? sv : -1e30f;
                s[a][bi][e] = sv;
                mx = fmaxf(mx, sv);
            }
        }
        mx = fmaxf(mx, __shfl_xor(mx, 16));
        mx = fmaxf(mx, __shfl_xor(mx, 32));
        float sum = 0.f;
        #pragma unroll
        for (int a = 0; a < 4; ++a) {
            #pragma unroll
            for (int e = 0; e < 4; ++e) {
                int j = a * 16 + g * 4 + e;
                float pv = (j < 49) ? __expf(s[a][bi][e] - mx) : 0.f;
                s[a][bi][e] = pv;
                sum += pv;
            }
        }
        sum += __shfl_xor(sum, 16);
        sum += __shfl_xor(sum, 32);
        float inv = 1.0f / sum;
        #pragma unroll
        for (int a = 0; a < 4; ++a)
            #pragma unroll
            for (int e = 0; e < 4; ++e)
                s[a][bi][e] *= inv;
    }

    unsigned pk[4][4][2];
    #pragma unroll
    for (int a = 0; a < 4; ++a)
        #pragma unroll
        for (int bi = 0; bi < 4; ++bi)
            #pragma unroll
            for (int h = 0; h < 2; ++h)
                pk[a][bi][h] = (unsigned)f2bf(s[a][bi][2 * h]) |
                               ((unsigned)f2bf(s[a][bi][2 * h + 1]) << 16);

    const unsigned short* vbase = vw + (size_t)win * 24576 + head * HD * 64;
    short8 vf[2][2];
    #pragma unroll
    for (int tn = 0; tn < 2; ++tn)
        #pragma unroll
        for (int ks = 0; ks < 2; ++ks)
            vf[tn][ks] = *(const short8*)(vbase + (tn * 16 + c) * 64 + ks * 32 + g * 8);

    f32x4 o[4][2] = {};
    const int gsel = g >> 1;
    const int sgb = 2 * (g & 1);
    #pragma unroll
    for (int ks = 0; ks < 2; ++ks) {
        #pragma unroll
        for (int to = 0; to < 4; ++to) {
            union { int w[4]; short8 v; } u;
            #pragma unroll
            for (int w = 0; w < 4; ++w) {
                int srcl = ((sgb + (w >> 1)) * 16 + c) << 2;
                int rA = __builtin_amdgcn_ds_bpermute(srcl, (int)pk[ks * 2 + 0][to][w & 1]);
                int rB = __builtin_amdgcn_ds_bpermute(srcl, (int)pk[ks * 2 + 1][to][w & 1]);
                u.w[w] = gsel ? rB : rA;
            }
            #pragma unroll
            for (int tn = 0; tn < 2; ++tn)
                o[to][tn] = __builtin_amdgcn_mfma_f32_16x16x32_bf16(u.v, vf[tn][ks], o[to][tn], 0, 0, 0);
        }
    }

    // store O rows i = to*16+g*4+e (i<49), cols d = tn*16+c, to spatial-major att
    const int wl = win & 63, bb = win >> 6;
    const size_t obase = (size_t)bb * 3136 * DIMC;
    const int nsp0 = (wl >> 3) * 7 * HWIMG + (wl & 7) * 7;
    #pragma unroll
    for (int to = 0; to < 4; ++to) {
        #pragma unroll
        for (int e = 0; e < 4; ++e) {
            int i = to * 16 + g * 4 + e;
            if (i < 49) {
                int nsp = nsp0 + (i / 7) * HWIMG + (i % 7);
                unsigned short* ob = att + obase + (size_t)nsp * DIMC + head * HD;
                #pragma unroll
                for (int tn = 0; tn < 2; ++tn)
                    ob[tn * 16 + c] = f2bf(o[to][tn][e]);
            }
        }
    }
}

extern "C" void kernel_launch(void* const* d_in, const int* in_sizes, int n_in,
                              void* d_out, int out_size, void* d_ws, size_t ws_size,
                              hipStream_t stream) {
    const float* x          = (const float*)d_in[0];
    const float* w_qkv      = (const float*)d_in[1];
    const float* w_proj     = (const float*)d_in[2];
    const float* b_proj     = (const float*)d_in[3];
    const float* bias_table = (const float*)d_in[4];
    const int*   rel_index  = (const int*)d_in[5];

    // workspace layout (att aliases xt: xt consumed by GEMM1 before att is written)
    unsigned short* xt   = (unsigned short*)d_ws;                    // [NROWS][384]
    unsigned short* att  = xt;                                       // alias, spatial-major
    unsigned short* qkw  = xt + (size_t)NROWS * KDIM;                // [NROWS][768]
    unsigned short* vw   = qkw + (size_t)NROWS * 768;                // [NWIN][384][64]
    unsigned short* wqb  = vw + (size_t)NWIN * 384 * 64;             // [1152][384]
    unsigned short* wpb  = wqb + QKV_M * KDIM;                       // [384][384]
    float*          biasp = (float*)(wpb + DIMC * KDIM);             // [12][64][64]

    cvt_w<<<(QKV_M * KDIM + 255) / 256, 256, 0, stream>>>(w_qkv, wqb, QKV_M * KDIM);
    cvt_w<<<(DIMC * KDIM + 255) / 256, 256, 0, stream>>>(w_proj, wpb, DIMC * KDIM);
    cvt_x<<<dim3(98, 12, BATCH), 256, 0, stream>>>(x, xt);
    fill_bias<<<192, 256, 0, stream>>>(bias_table, rel_index, biasp);
    zero_vpad<<<3072, 256, 0, stream>>>(vw);

    // GEMM1: 18 m-chunks x 98 n-chunks (8 tiles each) = 1764 blocks
    gemm_pa<0><<<1764, 256, 0, stream>>>(wqb, xt, nullptr, (void*)qkw, vw);

    // attention: 24576 (win,head) waves, 4 per block
    win_attn<<<6144, 256, 0, stream>>>(qkw, vw, biasp, att);

    // GEMM2: 6 m-chunks x 196 n-chunks (4 tiles each) = 1176 blocks
    gemm_pa<1><<<1176, 256, 0, stream>>>(wpb, att, b_proj, d_out, nullptr);
}